// Round 1
// baseline (397.761 us; speedup 1.0000x reference)
//
#include <hip/hip_runtime.h>

// GraphSAGE forward: CSR build (count/scan/scatter) + 4 fused level kernels
// (mean-agg + 2 small GEMMs, wave-per-node) + output projection.
// All f32. Workspace layout carved from d_ws (~30 MB needed).

__global__ __launch_bounds__(256) void k_count(const int* __restrict__ edst,
                                               int* __restrict__ deg, int E) {
    int t = blockIdx.x * blockDim.x + threadIdx.x;
    if (t < E) atomicAdd(&deg[edst[t]], 1);
}

__global__ __launch_bounds__(256) void k_blocksum(const int* __restrict__ deg,
                                                  int* __restrict__ bsums, int N) {
    __shared__ int s[256];
    int t = threadIdx.x;
    int base = blockIdx.x * 1024 + t * 4;
    int v = 0;
#pragma unroll
    for (int j = 0; j < 4; j++) { int idx = base + j; if (idx < N) v += deg[idx]; }
    s[t] = v; __syncthreads();
    for (int o = 128; o > 0; o >>= 1) { if (t < o) s[t] += s[t + o]; __syncthreads(); }
    if (t == 0) bsums[blockIdx.x] = s[0];
}

__global__ __launch_bounds__(256) void k_scantop(int* __restrict__ bsums, int NB) {
    __shared__ int s[256];
    int t = threadIdx.x;
    int v = (t < NB) ? bsums[t] : 0;
    s[t] = v; __syncthreads();
    for (int o = 1; o < 256; o <<= 1) {
        int x = (t >= o) ? s[t - o] : 0;
        __syncthreads();
        s[t] += x;
        __syncthreads();
    }
    if (t < NB) bsums[t] = s[t] - v;  // exclusive prefix of block sums
}

__global__ __launch_bounds__(256) void k_scanfinal(const int* __restrict__ deg,
                                                   const int* __restrict__ bsums,
                                                   int* __restrict__ offsets,
                                                   int* __restrict__ cursor,
                                                   float* __restrict__ inv_cnt,
                                                   int N, int E) {
    __shared__ int s[256];
    int t = threadIdx.x, b = blockIdx.x;
    int base = b * 1024 + t * 4;
    int d[4]; int lsum = 0;
#pragma unroll
    for (int j = 0; j < 4; j++) { int idx = base + j; d[j] = (idx < N) ? deg[idx] : 0; lsum += d[j]; }
    s[t] = lsum; __syncthreads();
    for (int o = 1; o < 256; o <<= 1) {
        int x = (t >= o) ? s[t - o] : 0;
        __syncthreads();
        s[t] += x;
        __syncthreads();
    }
    int p = bsums[b] + s[t] - lsum;  // exclusive prefix for this thread's 4 elems
#pragma unroll
    for (int j = 0; j < 4; j++) {
        int idx = base + j;
        if (idx < N) {
            offsets[idx] = p;
            cursor[idx] = p;
            inv_cnt[idx] = 1.0f / (float)(d[j] > 0 ? d[j] : 1);
            p += d[j];
        }
    }
    if (b == 0 && t == 0) offsets[N] = E;
}

__global__ __launch_bounds__(256) void k_scatter(const int* __restrict__ esrc,
                                                 const int* __restrict__ edst,
                                                 int* __restrict__ cursor,
                                                 int* __restrict__ csr, int E) {
    int t = blockIdx.x * blockDim.x + threadIdx.x;
    if (t < E) {
        int d = edst[t];
        int pos = atomicAdd(&cursor[d], 1);
        csr[pos] = esrc[t];
    }
}

// One wave per node: gather-mean neighbors (feature-parallel, coalesced),
// then a = relu(m@Wa), h = relu(a@We) with weights in LDS.
template <int DIN, int DMID, int DOUT>
__global__ __launch_bounds__(256) void k_level(const float* __restrict__ hprev,
                                               float* __restrict__ hnext,
                                               const int* __restrict__ offsets,
                                               const int* __restrict__ csr,
                                               const float* __restrict__ inv_cnt,
                                               const float* __restrict__ Wa,
                                               const float* __restrict__ We, int N) {
    __shared__ float sWa[DIN * DMID];
    __shared__ float sWe[DMID * DOUT];
    __shared__ float sM[4][64];
    __shared__ float sA[4][64];
    for (int i = threadIdx.x; i < DIN * DMID; i += blockDim.x) sWa[i] = Wa[i];
    for (int i = threadIdx.x; i < DMID * DOUT; i += blockDim.x) sWe[i] = We[i];
    __syncthreads();

    int lane = threadIdx.x & 63;
    int wid = threadIdx.x >> 6;
    int gw = blockIdx.x * 4 + wid;
    int nw = gridDim.x * 4;

    for (int node = gw; node < N; node += nw) {
        int start = offsets[node], end = offsets[node + 1];
        float a0 = 0.f, a1 = 0.f, a2 = 0.f, a3 = 0.f;
        for (int bb = start; bb < end; bb += 64) {
            int cnt = min(64, end - bb);
            int sidx = (lane < cnt) ? csr[bb + lane] : 0;  // lane-parallel index prefetch
            int i = 0;
            for (; i + 4 <= cnt; i += 4) {
                int s0 = __shfl(sidx, i);
                int s1 = __shfl(sidx, i + 1);
                int s2 = __shfl(sidx, i + 2);
                int s3 = __shfl(sidx, i + 3);
                if (lane < DIN) {
                    a0 += hprev[s0 * DIN + lane];
                    a1 += hprev[s1 * DIN + lane];
                    a2 += hprev[s2 * DIN + lane];
                    a3 += hprev[s3 * DIN + lane];
                }
            }
            for (; i < cnt; ++i) {
                int s0 = __shfl(sidx, i);
                if (lane < DIN) a0 += hprev[s0 * DIN + lane];
            }
        }
        float m = ((a0 + a1) + (a2 + a3)) * inv_cnt[node];
        if (lane < DIN) sM[wid][lane] = m;   // intra-wave LDS comm; compiler emits lgkmcnt waits
        if (lane < DMID) {
            float av = 0.f;
#pragma unroll
            for (int k = 0; k < DIN; k++) av += sM[wid][k] * sWa[k * DMID + lane];
            sA[wid][lane] = fmaxf(av, 0.f);
        }
        if (lane < DOUT) {
            float o = 0.f;
#pragma unroll
            for (int k = 0; k < DMID; k++) o += sA[wid][k] * sWe[k * DOUT + lane];
            hnext[node * DOUT + lane] = fmaxf(o, 0.f);
        }
    }
}

__global__ __launch_bounds__(256) void k_out(const float* __restrict__ h,
                                             const int* __restrict__ nodes,
                                             const float* __restrict__ Wout,
                                             float* __restrict__ out, int B) {
    __shared__ float sW[32 * 40];
    for (int i = threadIdx.x; i < 32 * 40; i += blockDim.x) sW[i] = Wout[i];
    __syncthreads();
    int t = blockIdx.x * blockDim.x + threadIdx.x;
    if (t >= B * 40) return;
    int i = t / 40, c = t - i * 40;
    const float* e = h + (long)nodes[i] * 32;
    float s = 0.f;
#pragma unroll
    for (int k = 0; k < 32; k++) s += e[k] * sW[k * 40 + c];
    out[t] = s;
}

extern "C" void kernel_launch(void* const* d_in, const int* in_sizes, int n_in,
                              void* d_out, int out_size, void* d_ws, size_t ws_size,
                              hipStream_t stream) {
    const float* raw  = (const float*)d_in[0];
    const int* nodes  = (const int*)d_in[1];
    const int* esrc   = (const int*)d_in[2];
    const int* edst   = (const int*)d_in[3];
    const float* Wa1 = (const float*)d_in[4];
    const float* Wa2 = (const float*)d_in[5];
    const float* Wa3 = (const float*)d_in[6];
    const float* Wa4 = (const float*)d_in[7];
    const float* We1 = (const float*)d_in[8];
    const float* We2 = (const float*)d_in[9];
    const float* We3 = (const float*)d_in[10];
    const float* We4 = (const float*)d_in[11];
    const float* Wout = (const float*)d_in[12];
    float* out = (float*)d_out;

    int N = in_sizes[1];   // 50000
    int E = in_sizes[2];   // 850000
    int B = N;

    char* p = (char*)d_ws;
    auto alloc = [&](size_t bytes) -> char* {
        char* r = p;
        p += (bytes + 255) & ~(size_t)255;
        return r;
    };
    int*   deg     = (int*)alloc((size_t)N * 4);
    int*   offsets = (int*)alloc((size_t)(N + 1) * 4);
    int*   cursor  = (int*)alloc((size_t)N * 4);
    float* inv_cnt = (float*)alloc((size_t)N * 4);
    int NB = (N + 1023) / 1024;
    int*   bsums   = (int*)alloc((size_t)NB * 4);
    int*   csr     = (int*)alloc((size_t)E * 4);
    float* hA      = (float*)alloc((size_t)N * 64 * 4);
    float* hB      = (float*)alloc((size_t)N * 64 * 4);
    (void)ws_size; (void)n_in; (void)out_size;

    hipMemsetAsync(deg, 0, (size_t)N * 4, stream);
    int eb = (E + 255) / 256;
    k_count<<<eb, 256, 0, stream>>>(edst, deg, E);
    k_blocksum<<<NB, 256, 0, stream>>>(deg, bsums, N);
    k_scantop<<<1, 256, 0, stream>>>(bsums, NB);
    k_scanfinal<<<NB, 256, 0, stream>>>(deg, bsums, offsets, cursor, inv_cnt, N, E);
    k_scatter<<<eb, 256, 0, stream>>>(esrc, edst, cursor, csr, E);

    const int LB = 1024;
    k_level<3, 32, 32><<<LB, 256, 0, stream>>>(raw, hA, offsets, csr, inv_cnt, Wa1, We1, N);
    k_level<32, 32, 64><<<LB, 256, 0, stream>>>(hA, hB, offsets, csr, inv_cnt, Wa2, We2, N);
    k_level<64, 64, 64><<<LB, 256, 0, stream>>>(hB, hA, offsets, csr, inv_cnt, Wa3, We3, N);
    k_level<64, 32, 32><<<LB, 256, 0, stream>>>(hA, hB, offsets, csr, inv_cnt, Wa4, We4, N);

    k_out<<<(B * 40 + 255) / 256, 256, 0, stream>>>(hB, nodes, Wout, out, B);
}

// Round 2
// 260.598 us; speedup vs baseline: 1.5263x; 1.5263x over previous
//
#include <hip/hip_runtime.h>

// GraphSAGE forward: CSR build (count/scan/scatter) + 4 fused level kernels
// (mean-agg + 2 small GEMMs) + output projection. All f32.
//
// Level kernels: lane-groups of GSIZE lanes gather one node via float2 loads
// (DIN==2*GSIZE) -> 64/GSIZE nodes in flight per wave. sM/sA slots are
// wave-private (no block syncs in the node loop). 512-thread blocks,
// launch_bounds(512,8) -> 32 waves/CU when LDS fits 4 blocks (level3 = 40960B exactly).

__global__ __launch_bounds__(256) void k_count(const int* __restrict__ edst,
                                               int* __restrict__ deg, int E) {
    int t = blockIdx.x * blockDim.x + threadIdx.x;
    if (t < E) atomicAdd(&deg[edst[t]], 1);
}

__global__ __launch_bounds__(256) void k_blocksum(const int* __restrict__ deg,
                                                  int* __restrict__ bsums, int N) {
    __shared__ int s[256];
    int t = threadIdx.x;
    int base = blockIdx.x * 1024 + t * 4;
    int v = 0;
#pragma unroll
    for (int j = 0; j < 4; j++) { int idx = base + j; if (idx < N) v += deg[idx]; }
    s[t] = v; __syncthreads();
    for (int o = 128; o > 0; o >>= 1) { if (t < o) s[t] += s[t + o]; __syncthreads(); }
    if (t == 0) bsums[blockIdx.x] = s[0];
}

__global__ __launch_bounds__(256) void k_scantop(int* __restrict__ bsums, int NB) {
    __shared__ int s[256];
    int t = threadIdx.x;
    int v = (t < NB) ? bsums[t] : 0;
    s[t] = v; __syncthreads();
    for (int o = 1; o < 256; o <<= 1) {
        int x = (t >= o) ? s[t - o] : 0;
        __syncthreads();
        s[t] += x;
        __syncthreads();
    }
    if (t < NB) bsums[t] = s[t] - v;  // exclusive prefix of block sums
}

__global__ __launch_bounds__(256) void k_scanfinal(const int* __restrict__ deg,
                                                   const int* __restrict__ bsums,
                                                   int* __restrict__ offsets,
                                                   int* __restrict__ cursor,
                                                   float* __restrict__ inv_cnt,
                                                   int N, int E) {
    __shared__ int s[256];
    int t = threadIdx.x, b = blockIdx.x;
    int base = b * 1024 + t * 4;
    int d[4]; int lsum = 0;
#pragma unroll
    for (int j = 0; j < 4; j++) { int idx = base + j; d[j] = (idx < N) ? deg[idx] : 0; lsum += d[j]; }
    s[t] = lsum; __syncthreads();
    for (int o = 1; o < 256; o <<= 1) {
        int x = (t >= o) ? s[t - o] : 0;
        __syncthreads();
        s[t] += x;
        __syncthreads();
    }
    int p = bsums[b] + s[t] - lsum;
#pragma unroll
    for (int j = 0; j < 4; j++) {
        int idx = base + j;
        if (idx < N) {
            offsets[idx] = p;
            cursor[idx] = p;
            inv_cnt[idx] = 1.0f / (float)(d[j] > 0 ? d[j] : 1);
            p += d[j];
        }
    }
    if (b == 0 && t == 0) offsets[N] = E;
}

__global__ __launch_bounds__(256) void k_scatter(const int* __restrict__ esrc,
                                                 const int* __restrict__ edst,
                                                 int* __restrict__ cursor,
                                                 int* __restrict__ csr, int E) {
    int t = blockIdx.x * blockDim.x + threadIdx.x;
    if (t < E) {
        int d = edst[t];
        int pos = atomicAdd(&cursor[d], 1);
        csr[pos] = esrc[t];
    }
}

// GSIZE lanes per node-group; NPG = 64/GSIZE nodes per wave.
// V2 (float2 gather) when DIN == 2*GSIZE; else scalar loads with lg<DIN active.
template <int DIN, int DMID, int DOUT, int GSIZE>
__global__ __launch_bounds__(512, 8) void k_level(
    const float* __restrict__ hprev, float* __restrict__ hnext,
    const int* __restrict__ offsets, const int* __restrict__ csr,
    const float* __restrict__ inv_cnt,
    const float* __restrict__ Wa, const float* __restrict__ We, int N) {
    constexpr int WAVES = 8;
    constexpr int NPG = 64 / GSIZE;
    constexpr int NPB = WAVES * NPG;
    constexpr bool V2 = (DIN == 2 * GSIZE);

    __shared__ float sWa[DIN * DMID];
    __shared__ float sWe[DMID * DOUT];
    __shared__ float sM[NPB * DIN];   // wave-private slots
    __shared__ float sA[NPB * DMID];  // wave-private slots

    for (int i = threadIdx.x; i < DIN * DMID; i += 512) sWa[i] = Wa[i];
    for (int i = threadIdx.x; i < DMID * DOUT; i += 512) sWe[i] = We[i];
    __syncthreads();

    const int lane = threadIdx.x & 63;
    const int wid  = threadIdx.x >> 6;
    const int g    = lane / GSIZE;
    const int lg   = lane & (GSIZE - 1);
    const int slot = wid * NPG + g;
    const int srcb = g * GSIZE;
    const long stride = (long)gridDim.x * NPB;

    for (long base = (long)blockIdx.x * NPB; base < N; base += stride) {
        int node = (int)base + slot;
        if (node < N) {
            int start = offsets[node], end = offsets[node + 1];
            float m0 = 0, m1 = 0, n0 = 0, n1 = 0, p0 = 0, p1 = 0, q0 = 0, q1 = 0;
            for (int bb = start; bb < end; bb += GSIZE) {
                int cnt = min(GSIZE, end - bb);
                int sidx = (lg < cnt) ? csr[bb + lg] : 0;
                int i = 0;
                for (; i + 4 <= cnt; i += 4) {
                    int s0 = __shfl(sidx, srcb + i);
                    int s1 = __shfl(sidx, srcb + i + 1);
                    int s2 = __shfl(sidx, srcb + i + 2);
                    int s3 = __shfl(sidx, srcb + i + 3);
                    if (V2) {
                        const float2* hp = (const float2*)hprev;
                        float2 v0 = hp[(long)s0 * (DIN / 2) + lg];
                        float2 v1 = hp[(long)s1 * (DIN / 2) + lg];
                        float2 v2 = hp[(long)s2 * (DIN / 2) + lg];
                        float2 v3 = hp[(long)s3 * (DIN / 2) + lg];
                        m0 += v0.x; m1 += v0.y;
                        n0 += v1.x; n1 += v1.y;
                        p0 += v2.x; p1 += v2.y;
                        q0 += v3.x; q1 += v3.y;
                    } else if (lg < DIN) {
                        m0 += hprev[(long)s0 * DIN + lg];
                        n0 += hprev[(long)s1 * DIN + lg];
                        p0 += hprev[(long)s2 * DIN + lg];
                        q0 += hprev[(long)s3 * DIN + lg];
                    }
                }
                for (; i < cnt; ++i) {
                    int s0 = __shfl(sidx, srcb + i);
                    if (V2) {
                        const float2* hp = (const float2*)hprev;
                        float2 v0 = hp[(long)s0 * (DIN / 2) + lg];
                        m0 += v0.x; m1 += v0.y;
                    } else if (lg < DIN) {
                        m0 += hprev[(long)s0 * DIN + lg];
                    }
                }
            }
            float ic = inv_cnt[node];
            float fx = ((m0 + n0) + (p0 + q0)) * ic;
            if (V2) {
                float fy = ((m1 + n1) + (p1 + q1)) * ic;
                sM[slot * DIN + 2 * lg]     = fx;
                sM[slot * DIN + 2 * lg + 1] = fy;
            } else if (lg < DIN) {
                sM[slot * DIN + lg] = fx;
            }
        }
        // a = relu(m @ Wa) — all 64 lanes over the wave's NPG*DMID outputs
        constexpr int AO = NPG * DMID;
#pragma unroll
        for (int r = 0; r < AO / 64; ++r) {
            int oi = r * 64 + lane;
            int sl = wid * NPG + oi / DMID;
            int col = oi & (DMID - 1);
            if ((int)base + sl < N) {
                float v = 0.f;
#pragma unroll
                for (int k = 0; k < DIN; ++k) v += sM[sl * DIN + k] * sWa[k * DMID + col];
                sA[sl * DMID + col] = fmaxf(v, 0.f);
            }
        }
        // h = relu(a @ We)
        constexpr int HO = NPG * DOUT;
#pragma unroll
        for (int r = 0; r < HO / 64; ++r) {
            int oi = r * 64 + lane;
            int sl = wid * NPG + oi / DOUT;
            int col = oi & (DOUT - 1);
            int nd = (int)base + sl;
            if (nd < N) {
                float v = 0.f;
#pragma unroll
                for (int k = 0; k < DMID; ++k) v += sA[sl * DMID + k] * sWe[k * DOUT + col];
                hnext[(long)nd * DOUT + col] = fmaxf(v, 0.f);
            }
        }
    }
}

__global__ __launch_bounds__(256) void k_out(const float* __restrict__ h,
                                             const int* __restrict__ nodes,
                                             const float* __restrict__ Wout,
                                             float* __restrict__ out, int B) {
    __shared__ float sW[32 * 40];
    for (int i = threadIdx.x; i < 32 * 40; i += blockDim.x) sW[i] = Wout[i];
    __syncthreads();
    int t = blockIdx.x * blockDim.x + threadIdx.x;
    if (t >= B * 40) return;
    int i = t / 40, c = t - i * 40;
    const float* e = h + (long)nodes[i] * 32;
    float s = 0.f;
#pragma unroll
    for (int k = 0; k < 32; k++) s += e[k] * sW[k * 40 + c];
    out[t] = s;
}

extern "C" void kernel_launch(void* const* d_in, const int* in_sizes, int n_in,
                              void* d_out, int out_size, void* d_ws, size_t ws_size,
                              hipStream_t stream) {
    const float* raw  = (const float*)d_in[0];
    const int* nodes  = (const int*)d_in[1];
    const int* esrc   = (const int*)d_in[2];
    const int* edst   = (const int*)d_in[3];
    const float* Wa1 = (const float*)d_in[4];
    const float* Wa2 = (const float*)d_in[5];
    const float* Wa3 = (const float*)d_in[6];
    const float* Wa4 = (const float*)d_in[7];
    const float* We1 = (const float*)d_in[8];
    const float* We2 = (const float*)d_in[9];
    const float* We3 = (const float*)d_in[10];
    const float* We4 = (const float*)d_in[11];
    const float* Wout = (const float*)d_in[12];
    float* out = (float*)d_out;

    int N = in_sizes[1];   // 50000
    int E = in_sizes[2];   // 850000
    int B = N;

    char* p = (char*)d_ws;
    auto alloc = [&](size_t bytes) -> char* {
        char* r = p;
        p += (bytes + 255) & ~(size_t)255;
        return r;
    };
    int*   deg     = (int*)alloc((size_t)N * 4);
    int*   offsets = (int*)alloc((size_t)(N + 1) * 4);
    int*   cursor  = (int*)alloc((size_t)N * 4);
    float* inv_cnt = (float*)alloc((size_t)N * 4);
    int NB = (N + 1023) / 1024;
    int*   bsums   = (int*)alloc((size_t)NB * 4);
    int*   csr     = (int*)alloc((size_t)E * 4);
    float* hA      = (float*)alloc((size_t)N * 64 * 4);
    float* hB      = (float*)alloc((size_t)N * 64 * 4);
    (void)ws_size; (void)n_in; (void)out_size;

    hipMemsetAsync(deg, 0, (size_t)N * 4, stream);
    int eb = (E + 255) / 256;
    k_count<<<eb, 256, 0, stream>>>(edst, deg, E);
    k_blocksum<<<NB, 256, 0, stream>>>(deg, bsums, N);
    k_scantop<<<1, 256, 0, stream>>>(bsums, NB);
    k_scanfinal<<<NB, 256, 0, stream>>>(deg, bsums, offsets, cursor, inv_cnt, N, E);
    k_scatter<<<eb, 256, 0, stream>>>(esrc, edst, cursor, csr, E);

    auto blocksFor = [](int n, int npb) {
        int b = (n + npb - 1) / npb;
        return b < 2048 ? b : 2048;
    };
    k_level<3, 32, 32, 4><<<blocksFor(N, 128), 512, 0, stream>>>(raw, hA, offsets, csr, inv_cnt, Wa1, We1, N);
    k_level<32, 32, 64, 16><<<blocksFor(N, 32), 512, 0, stream>>>(hA, hB, offsets, csr, inv_cnt, Wa2, We2, N);
    k_level<64, 64, 64, 32><<<blocksFor(N, 16), 512, 0, stream>>>(hB, hA, offsets, csr, inv_cnt, Wa3, We3, N);
    k_level<64, 32, 32, 32><<<blocksFor(N, 16), 512, 0, stream>>>(hA, hB, offsets, csr, inv_cnt, Wa4, We4, N);

    k_out<<<(B * 40 + 255) / 256, 256, 0, stream>>>(hB, nodes, Wout, out, B);
}